// Round 3
// baseline (819.238 us; speedup 1.0000x reference)
//
#include <hip/hip_runtime.h>
#include <hip/hip_bf16.h>

#define BB 512      // batch
#define DD 2048     // input dim
#define KK 4096     // code dim
#define CC 512      // cause dim
#define LR 0.001f
#define GAMMA 0.1f

typedef __attribute__((ext_vector_type(8))) short short8;
typedef __attribute__((ext_vector_type(4))) float f32x4;

__device__ __forceinline__ unsigned short f2bf(float f) {
  union { float f; unsigned u; } x; x.f = f;
  unsigned r = x.u + 0x7FFF + ((x.u >> 16) & 1);   // RNE
  return (unsigned short)(r >> 16);
}

__device__ __forceinline__ void g2l16(const void* g, void* l) {
  __builtin_amdgcn_global_load_lds(
      (const __attribute__((address_space(1))) void*)g,
      (__attribute__((address_space(3))) void*)l, 16, 0, 0);
}

__device__ __forceinline__ void store4bf(unsigned short* p, f32x4 v) {
  const unsigned lo = (unsigned)f2bf(v[0]) | ((unsigned)f2bf(v[1]) << 16);
  const unsigned hi = (unsigned)f2bf(v[2]) | ((unsigned)f2bf(v[3]) << 16);
  *(uint2*)p = uint2{lo, hi};
}

// ---------------------------------------------------------------------------
// 64x64-tile GEMM, C[M,N](+epi) = A[M,Kslice] @ Bm[N,Kslice]^T, K-major bf16.
// 4 waves (2x2), wave tile 32x32, BK=64. LDS XOR-swizzled (rule #21: linear
// global_load_lds dest + pre-swizzled global source + XOR on ds_read).
// Single-barrier double-buffered pipeline: stage t+1 while computing t.
// MODE 0: p1[idx] = acc                         (z fp32 / final out)
// MODE 1: h0[idx] = bf16(acc - p0[idx])         (r = out - inputs)
// MODE 2: gradx+prox: p0=z, p1=x(io), h0=xb, h1=g
// MODE 3: partials:   p1[bz*M*N + idx] = acc    (gu split-K)
// ---------------------------------------------------------------------------
template<int MODE>
__global__ __launch_bounds__(256, 4)
void gemm64(const unsigned short* __restrict__ A,
            const unsigned short* __restrict__ Bm,
            int M, int N, int Kd, int kslice,
            const float* __restrict__ p0,
            float* __restrict__ p1,
            unsigned short* __restrict__ h0,
            unsigned short* __restrict__ h1) {
  __shared__ unsigned short As[2][64 * 64];   // 8 KB each
  __shared__ unsigned short Bs[2][64 * 64];
  const int tid = threadIdx.x;
  const int w   = tid >> 6;             // wave 0..3
  const int l   = tid & 63;
  const int bm  = blockIdx.y * 64;
  const int bn  = blockIdx.x * 64;
  const int kbase = blockIdx.z * kslice;
  const int wr  = w >> 1, wc = w & 1;   // 2x2 wave grid, 32x32 each
  const int fr  = l & 15, fq = l >> 4;  // fragment row / k-quarter

  // staging lane map: call c covers rows c*32..c*32+31; lane handles
  // row = c*32 + w*8 + (l>>3), global col pre-swizzled by row&7 (= l>>3)
  const int srow = w * 8 + (l >> 3);
  const int scol = 8 * ((l & 7) ^ (l >> 3));
  const unsigned short* ag = A  + (size_t)(bm + srow) * Kd + kbase + scol;
  const unsigned short* bg = Bm + (size_t)(bn + srow) * Kd + kbase + scol;
  const int lbase = w * 512;            // wave-uniform LDS elem offset

  f32x4 acc[2][2];
#pragma unroll
  for (int m = 0; m < 2; m++)
#pragma unroll
    for (int n = 0; n < 2; n++) acc[m][n] = f32x4{0.f, 0.f, 0.f, 0.f};

  const int nt = kslice >> 6;

  // prologue: stage tile 0 into buf 0
  g2l16(ag, &As[0][lbase]);
  g2l16(ag + (size_t)32 * Kd, &As[0][2048 + lbase]);
  g2l16(bg, &Bs[0][lbase]);
  g2l16(bg + (size_t)32 * Kd, &Bs[0][2048 + lbase]);
  asm volatile("s_waitcnt vmcnt(0)" ::: "memory");
  __builtin_amdgcn_s_barrier();

  for (int t = 0; t < nt; t++) {
    const int cur = t & 1;
    if (t + 1 < nt) {
      const int k0 = (t + 1) << 6;
      const int nb = cur ^ 1;
      g2l16(ag + k0, &As[nb][lbase]);
      g2l16(ag + (size_t)32 * Kd + k0, &As[nb][2048 + lbase]);
      g2l16(bg + k0, &Bs[nb][lbase]);
      g2l16(bg + (size_t)32 * Kd + k0, &Bs[nb][2048 + lbase]);
    }
#pragma unroll
    for (int kk = 0; kk < 2; kk++) {
      const int kx = (kk * 64 + fq * 16) ^ ((fr & 7) << 4);
      short8 af[2], bf[2];
#pragma unroll
      for (int m = 0; m < 2; m++) {
        const int rr = wr * 32 + m * 16 + fr;
        af[m] = *(const short8*)((const char*)&As[cur][0] + rr * 128 + kx);
      }
#pragma unroll
      for (int n = 0; n < 2; n++) {
        const int rr = wc * 32 + n * 16 + fr;
        bf[n] = *(const short8*)((const char*)&Bs[cur][0] + rr * 128 + kx);
      }
#pragma unroll
      for (int m = 0; m < 2; m++)
#pragma unroll
        for (int n = 0; n < 2; n++)
          acc[m][n] = __builtin_amdgcn_mfma_f32_16x16x32_bf16(af[m], bf[n], acc[m][n], 0, 0, 0);
    }
    asm volatile("s_waitcnt lgkmcnt(0)" ::: "memory");  // my ds_reads done
    asm volatile("s_waitcnt vmcnt(0)" ::: "memory");    // my stages done
    __builtin_amdgcn_s_barrier();
  }

  // Epilogue. C/D layout: col = lane&15, row = (lane>>4)*4 + j
  float* dstp = (MODE == 3) ? (p1 + (size_t)blockIdx.z * M * N) : p1;
#pragma unroll
  for (int m = 0; m < 2; m++) {
#pragma unroll
    for (int n = 0; n < 2; n++) {
#pragma unroll
      for (int j = 0; j < 4; j++) {
        const int row = bm + wr * 32 + m * 16 + fq * 4 + j;
        const int col = bn + wc * 32 + n * 16 + fr;
        const size_t idx = (size_t)row * N + col;
        const float v = acc[m][n][j];
        if constexpr (MODE == 0) {
          dstp[idx] = v;
        } else if constexpr (MODE == 1) {
          h0[idx] = f2bf(v - p0[idx]);
        } else if constexpr (MODE == 2) {
          const float zv = p0[idx];
          const float e = __expf(-zv);
          const float thr = (LR * GAMMA * 0.5f) * (1.0f + e);
          const float xv = p1[idx] - (2.0f * LR) * v;
          const float xn = fmaxf(xv - thr, 0.f) + fminf(xv + thr, 0.f);
          p1[idx] = xn;
          h0[idx] = f2bf(xn);
          h1[idx] = f2bf((-0.5f * GAMMA) * e * fabsf(xn));
        } else {  // MODE 3
          dstp[idx] = v;
        }
      }
    }
  }
}

// u-update: gu = sum(part[0..7]) + 0.02*GAMMA*u; prox; writes u, ub  over BB*CC
__global__ __launch_bounds__(256) void ep_u_k(const float* __restrict__ part,
                                              float* __restrict__ u,
                                              unsigned short* __restrict__ ub) {
  const int i = blockIdx.x * 256 + threadIdx.x;
  f32x4 v = f32x4{0.f, 0.f, 0.f, 0.f};
#pragma unroll
  for (int k = 0; k < 8; k++) v += ((const f32x4*)(part + (size_t)k * BB * CC))[i];
  const f32x4 uo = ((const f32x4*)u)[i];
  f32x4 un;
#pragma unroll
  for (int j = 0; j < 4; j++) {
    const float gu = v[j] + (0.02f * GAMMA) * uo[j];
    const float uu = uo[j] - LR * gu;
    un[j] = fmaxf(uu - (LR * GAMMA), 0.f) + fminf(uu + (LR * GAMMA), 0.f);
  }
  ((f32x4*)u)[i] = un;
  store4bf(ub + (size_t)i * 4, un);
}

// ---- one-time conversion / init kernels ----

// writes BOTH straight bf16 copy (b) and bf16 transpose (t) of src (R x C)
__global__ __launch_bounds__(256)
void convtrans_k(const float* __restrict__ src, unsigned short* __restrict__ b,
                 unsigned short* __restrict__ t, int R, int C) {
  __shared__ float tile[64][65];
  const int tid = threadIdx.x;
  const int tr = blockIdx.y * 64;
  const int tc = blockIdx.x * 64;
  const int lr = tid >> 4;
  const int lc = (tid & 15) * 4;
#pragma unroll
  for (int i = 0; i < 4; i++) {
    const float4 v = *(const float4*)(src + (size_t)(tr + lr + 16 * i) * C + tc + lc);
    tile[lr + 16 * i][lc + 0] = v.x;
    tile[lr + 16 * i][lc + 1] = v.y;
    tile[lr + 16 * i][lc + 2] = v.z;
    tile[lr + 16 * i][lc + 3] = v.w;
    f32x4 vv = f32x4{v.x, v.y, v.z, v.w};
    store4bf(b + (size_t)(tr + lr + 16 * i) * C + tc + lc, vv);
  }
  __syncthreads();
#pragma unroll
  for (int j = 0; j < 16; j++) {
    const int idx = tid + j * 256;
    const int c = idx >> 6;
    const int r = idx & 63;
    t[(size_t)(tc + c) * R + tr + r] = f2bf(tile[r][c]);
  }
}

__global__ void zero_k(unsigned int* p, int n) {
  const int i = blockIdx.x * blockDim.x + threadIdx.x;
  if (i < n) p[i] = 0u;
}

__global__ void initu_k(const float* __restrict__ u0, float* __restrict__ u,
                        unsigned short* __restrict__ ub, int n) {
  const int i = blockIdx.x * blockDim.x + threadIdx.x;
  if (i < n) {
    const float v = u0[i];
    u[i] = v;
    ub[i] = f2bf(v);
  }
}

// r = bf16(-inputs)   (step 0: x=0 so out=0)
__global__ __launch_bounds__(256) void r0_k(const float* __restrict__ inputs,
                                            unsigned short* __restrict__ r) {
  const int i = blockIdx.x * 256 + threadIdx.x;
  const f32x4 v = ((const f32x4*)inputs)[i];
  store4bf(r + (size_t)i * 4, f32x4{0.f, 0.f, 0.f, 0.f} - v);
}

extern "C" void kernel_launch(void* const* d_in, const int* in_sizes, int n_in,
                              void* d_out, int out_size, void* d_ws, size_t ws_size,
                              hipStream_t stream) {
  const float* inputs = (const float*)d_in[0];   // (BB, DD)
  const float* W      = (const float*)d_in[1];   // (KK, DD)
  const float* V      = (const float*)d_in[2];   // (CC, KK)
  const float* u0     = (const float*)d_in[3];   // (BB, CC)
  float* out = (float*)d_out;                    // (BB, DD)

  char* ws = (char*)d_ws;
  size_t off = 0;
  auto alloc = [&](size_t bytes) -> void* {
    void* p = ws + off;
    off += (bytes + 255) & ~(size_t)255;
    return p;
  };
  unsigned short* Wb = (unsigned short*)alloc((size_t)KK * DD * 2);  // W  (KK,DD) bf16
  unsigned short* Wt = (unsigned short*)alloc((size_t)DD * KK * 2);  // W^T (DD,KK) bf16
  unsigned short* Vb = (unsigned short*)alloc((size_t)CC * KK * 2);  // V  (CC,KK) bf16
  unsigned short* Vt = (unsigned short*)alloc((size_t)KK * CC * 2);  // V^T (KK,CC) bf16
  unsigned short* xb = (unsigned short*)alloc((size_t)BB * KK * 2);  // x bf16
  unsigned short* g  = (unsigned short*)alloc((size_t)BB * KK * 2);  // dcost_dz bf16
  unsigned short* r  = (unsigned short*)alloc((size_t)BB * DD * 2);  // out-inputs bf16
  unsigned short* ub = (unsigned short*)alloc((size_t)BB * CC * 2);  // u bf16
  float* x = (float*)alloc((size_t)BB * KK * 4);
  float* z = (float*)alloc((size_t)BB * KK * 4);
  float* u = (float*)alloc((size_t)BB * CC * 4);
  float* part = (float*)alloc((size_t)8 * BB * CC * 4);  // gu split-K partials

  // one-time conversions / init
  convtrans_k<<<dim3(DD / 64, KK / 64), 256, 0, stream>>>(W, Wb, Wt, KK, DD);
  convtrans_k<<<dim3(KK / 64, CC / 64), 256, 0, stream>>>(V, Vb, Vt, CC, KK);
  zero_k<<<(BB * KK / 2 + 255) / 256, 256, 0, stream>>>((unsigned int*)xb, BB * KK / 2);
  zero_k<<<(BB * KK + 255) / 256, 256, 0, stream>>>((unsigned int*)x, BB * KK);
  initu_k<<<(BB * CC + 255) / 256, 256, 0, stream>>>(u0, u, ub, BB * CC);
  r0_k<<<BB * DD / 4 / 256, 256, 0, stream>>>(inputs, r);

  for (int t = 0; t < 10; t++) {
    if (t > 0) {
      if (t < 9) {
        // r = bf16(x@W - inputs): 32x8 = 256 wgs
        gemm64<1><<<dim3(DD / 64, BB / 64), 256, 0, stream>>>(
            xb, Wt, BB, DD, KK, KK, inputs, nullptr, r, nullptr);
      } else {
        // final: d_out = x@W fp32
        gemm64<0><<<dim3(DD / 64, BB / 64), 256, 0, stream>>>(
            xb, Wt, BB, DD, KK, KK, nullptr, out, nullptr, nullptr);
        break;
      }
    }
    // z = u@V: 64x8 = 512 wgs
    gemm64<0><<<dim3(KK / 64, BB / 64), 256, 0, stream>>>(
        ub, Vt, BB, KK, CC, CC, nullptr, z, nullptr, nullptr);
    // gradx = 2*r@W^T fused prox-x: 64x8 = 512 wgs
    gemm64<2><<<dim3(KK / 64, BB / 64), 256, 0, stream>>>(
        r, Wb, BB, KK, DD, DD, z, x, xb, g);
    // gu partials: g@V^T split-K=8: 8x8x8 = 512 wgs
    gemm64<3><<<dim3(CC / 64, BB / 64, 8), 256, 0, stream>>>(
        g, Vb, BB, CC, KK, KK / 8, nullptr, part, nullptr, nullptr);
    // u prox update
    ep_u_k<<<BB * CC / 4 / 256, 256, 0, stream>>>(part, u, ub);
  }
}

// Round 4
// 690.560 us; speedup vs baseline: 1.1863x; 1.1863x over previous
//
#include <hip/hip_runtime.h>
#include <hip/hip_bf16.h>

#define BB 512      // batch
#define DD 2048     // input dim
#define KK 4096     // code dim
#define CC 512      // cause dim
#define LR 0.001f
#define GAMMA 0.1f

typedef __attribute__((ext_vector_type(8))) short short8;
typedef __attribute__((ext_vector_type(4))) float f32x4;

__device__ __forceinline__ unsigned short f2bf(float f) {
  union { float f; unsigned u; } x; x.f = f;
  unsigned r = x.u + 0x7FFF + ((x.u >> 16) & 1);   // RNE
  return (unsigned short)(r >> 16);
}

__device__ __forceinline__ void g2l16(const void* g, void* l) {
  __builtin_amdgcn_global_load_lds(
      (const __attribute__((address_space(1))) void*)g,
      (__attribute__((address_space(3))) void*)l, 16, 0, 0);
}

__device__ __forceinline__ void store4bf(unsigned short* p, f32x4 v) {
  const unsigned lo = (unsigned)f2bf(v[0]) | ((unsigned)f2bf(v[1]) << 16);
  const unsigned hi = (unsigned)f2bf(v[2]) | ((unsigned)f2bf(v[3]) << 16);
  *(uint2*)p = uint2{lo, hi};
}

// ---------------------------------------------------------------------------
// Pipelined 64x64-tile K-loop, BK=64, 4 waves (2x2), wave tile 32x32.
// 4 LDS buffer sets, 3 tiles staged ahead, counted vmcnt (T4), ONE barrier
// per iteration. LDS XOR-swizzle via pre-swizzled global source (rule #21).
// ag/bg: lane-adjusted bases (row = bm + w*8 + (l>>3), col pre-swizzled).
// Safety of single barrier: a wave's tile-(t-1) ds_reads are consumed by its
// MFMAs before it reaches barrier(t); stage(t+3) into buf[(t+3)&3]=(t-1)&3
// happens after barrier(t), so no wave still needs that buffer.
// ---------------------------------------------------------------------------
__device__ __forceinline__ void mm_pipe(
    const unsigned short* __restrict__ ag,
    const unsigned short* __restrict__ bg,
    int Kd, int nt,
    unsigned short* As, unsigned short* Bs,   // [4][4096] each
    int lbase, int fr, int fq, int wr, int wc,
    f32x4 acc[2][2]) {
  // prologue: stage tiles 0,1,2
#pragma unroll
  for (int p = 0; p < 3; p++) {
    const int k0 = p << 6;
    unsigned short* Ab = As + p * 4096;
    unsigned short* Bb = Bs + p * 4096;
    g2l16(ag + k0, Ab + lbase);
    g2l16(ag + (size_t)32 * Kd + k0, Ab + 2048 + lbase);
    g2l16(bg + k0, Bb + lbase);
    g2l16(bg + (size_t)32 * Kd + k0, Bb + 2048 + lbase);
  }
  for (int t = 0; t < nt; t++) {
    // wait for tile t's 4 loads only (keep up to 8 in flight)
    if (t + 3 <= nt)      asm volatile("s_waitcnt vmcnt(8)" ::: "memory");
    else if (t + 2 == nt) asm volatile("s_waitcnt vmcnt(4)" ::: "memory");
    else                  asm volatile("s_waitcnt vmcnt(0)" ::: "memory");
    __builtin_amdgcn_s_barrier();

    const unsigned short* Ab = As + (t & 3) * 4096;
    const unsigned short* Bb = Bs + (t & 3) * 4096;
#pragma unroll
    for (int kk = 0; kk < 2; kk++) {
      const int kx = (kk * 64 + fq * 16) ^ ((fr & 7) << 4);
      short8 af[2], bf2[2];
#pragma unroll
      for (int m = 0; m < 2; m++)
        af[m] = *(const short8*)((const char*)Ab + (wr * 32 + m * 16 + fr) * 128 + kx);
#pragma unroll
      for (int n = 0; n < 2; n++)
        bf2[n] = *(const short8*)((const char*)Bb + (wc * 32 + n * 16 + fr) * 128 + kx);
#pragma unroll
      for (int m = 0; m < 2; m++)
#pragma unroll
        for (int n = 0; n < 2; n++)
          acc[m][n] = __builtin_amdgcn_mfma_f32_16x16x32_bf16(af[m], bf2[n], acc[m][n], 0, 0, 0);
    }

    if (t + 3 < nt) {
      const int k0 = (t + 3) << 6;
      unsigned short* An = As + ((t + 3) & 3) * 4096;
      unsigned short* Bn = Bs + ((t + 3) & 3) * 4096;
      g2l16(ag + k0, An + lbase);
      g2l16(ag + (size_t)32 * Kd + k0, An + 2048 + lbase);
      g2l16(bg + k0, Bn + lbase);
      g2l16(bg + (size_t)32 * Kd + k0, Bn + 2048 + lbase);
    }
  }
}

#define LANE_SETUP                                             \
  const int tid = threadIdx.x;                                 \
  const int w = tid >> 6, l = tid & 63;                        \
  const int wr = w >> 1, wc = w & 1;                           \
  const int fr = l & 15, fq = l >> 4;                          \
  const int srow = w * 8 + (l >> 3);                           \
  const int scol = 8 * ((l & 7) ^ (l >> 3));                   \
  const int lbase = w * 512;

// out = x@W (+ r epilogue).  FINAL=0: h0 = bf16(acc - p0). FINAL=1: p1 = acc.
template<int FINAL>
__global__ __launch_bounds__(256, 2)
void outr_k(const unsigned short* __restrict__ A,   // xb (BB,KK)
            const unsigned short* __restrict__ Bm,  // Wt (DD,KK)
            const float* __restrict__ p0,           // inputs
            float* __restrict__ p1,                 // out (FINAL)
            unsigned short* __restrict__ h0) {      // r
  __shared__ unsigned short As[4][4096];
  __shared__ unsigned short Bs[4][4096];
  LANE_SETUP
  const int bm = blockIdx.y * 64, bn = blockIdx.x * 64;
  f32x4 acc[2][2];
#pragma unroll
  for (int m = 0; m < 2; m++)
#pragma unroll
    for (int n = 0; n < 2; n++) acc[m][n] = f32x4{0.f, 0.f, 0.f, 0.f};

  mm_pipe(A + (size_t)(bm + srow) * KK + scol,
          Bm + (size_t)(bn + srow) * KK + scol,
          KK, KK / 64, &As[0][0], &Bs[0][0], lbase, fr, fq, wr, wc, acc);

#pragma unroll
  for (int m = 0; m < 2; m++)
#pragma unroll
    for (int n = 0; n < 2; n++)
#pragma unroll
      for (int j = 0; j < 4; j++) {
        const int row = bm + wr * 32 + m * 16 + fq * 4 + j;
        const int col = bn + wc * 32 + n * 16 + fr;
        const size_t idx = (size_t)row * DD + col;
        if constexpr (FINAL) p1[idx] = acc[m][n][j];
        else                 h0[idx] = f2bf(acc[m][n][j] - p0[idx]);
      }
}

// fused: acc_z = u@V (K=CC), acc_gx = r@W^T (K=DD), then prox-x epilogue.
__global__ __launch_bounds__(256, 2)
void zgx_k(const unsigned short* __restrict__ ub,   // (BB,CC)
           const unsigned short* __restrict__ Vt,   // (KK,CC)
           const unsigned short* __restrict__ r,    // (BB,DD)
           const unsigned short* __restrict__ Wb,   // (KK,DD)
           float* __restrict__ x,                   // io
           unsigned short* __restrict__ xb,
           unsigned short* __restrict__ g) {
  __shared__ unsigned short As[4][4096];
  __shared__ unsigned short Bs[4][4096];
  LANE_SETUP
  const int bm = blockIdx.y * 64, bn = blockIdx.x * 64;
  f32x4 accz[2][2], accg[2][2];
#pragma unroll
  for (int m = 0; m < 2; m++)
#pragma unroll
    for (int n = 0; n < 2; n++) {
      accz[m][n] = f32x4{0.f, 0.f, 0.f, 0.f};
      accg[m][n] = f32x4{0.f, 0.f, 0.f, 0.f};
    }

  mm_pipe(ub + (size_t)(bm + srow) * CC + scol,
          Vt + (size_t)(bn + srow) * CC + scol,
          CC, CC / 64, &As[0][0], &Bs[0][0], lbase, fr, fq, wr, wc, accz);
  mm_pipe(r + (size_t)(bm + srow) * DD + scol,
          Wb + (size_t)(bn + srow) * DD + scol,
          DD, DD / 64, &As[0][0], &Bs[0][0], lbase, fr, fq, wr, wc, accg);

#pragma unroll
  for (int m = 0; m < 2; m++)
#pragma unroll
    for (int n = 0; n < 2; n++)
#pragma unroll
      for (int j = 0; j < 4; j++) {
        const int row = bm + wr * 32 + m * 16 + fq * 4 + j;
        const int col = bn + wc * 32 + n * 16 + fr;
        const size_t idx = (size_t)row * KK + col;
        const float e = __expf(-accz[m][n][j]);
        const float thr = (LR * GAMMA * 0.5f) * (1.0f + e);
        const float xv = x[idx] - (2.0f * LR) * accg[m][n][j];
        const float xn = fmaxf(xv - thr, 0.f) + fminf(xv + thr, 0.f);
        x[idx] = xn;
        xb[idx] = f2bf(xn);
        g[idx] = f2bf((-0.5f * GAMMA) * e * fabsf(xn));
      }
}

// gu partials: part[z*BB*CC + idx] = g@V^T over K-slice
__global__ __launch_bounds__(256, 2)
void gu_k(const unsigned short* __restrict__ g,    // (BB,KK)
          const unsigned short* __restrict__ Vb,   // (CC,KK)
          float* __restrict__ part) {
  __shared__ unsigned short As[4][4096];
  __shared__ unsigned short Bs[4][4096];
  LANE_SETUP
  const int bm = blockIdx.y * 64, bn = blockIdx.x * 64;
  const int kbase = blockIdx.z * (KK / 8);
  f32x4 acc[2][2];
#pragma unroll
  for (int m = 0; m < 2; m++)
#pragma unroll
    for (int n = 0; n < 2; n++) acc[m][n] = f32x4{0.f, 0.f, 0.f, 0.f};

  mm_pipe(g  + (size_t)(bm + srow) * KK + kbase + scol,
          Vb + (size_t)(bn + srow) * KK + kbase + scol,
          KK, (KK / 8) / 64, &As[0][0], &Bs[0][0], lbase, fr, fq, wr, wc, acc);

  float* dst = part + (size_t)blockIdx.z * BB * CC;
#pragma unroll
  for (int m = 0; m < 2; m++)
#pragma unroll
    for (int n = 0; n < 2; n++)
#pragma unroll
      for (int j = 0; j < 4; j++) {
        const int row = bm + wr * 32 + m * 16 + fq * 4 + j;
        const int col = bn + wc * 32 + n * 16 + fr;
        dst[(size_t)row * CC + col] = acc[m][n][j];
      }
}

// u-update: gu = sum(part[0..7]) + 0.02*GAMMA*u; prox; writes u, ub
__global__ __launch_bounds__(256) void ep_u_k(const float* __restrict__ part,
                                              float* __restrict__ u,
                                              unsigned short* __restrict__ ub) {
  const int i = blockIdx.x * 256 + threadIdx.x;
  f32x4 v = f32x4{0.f, 0.f, 0.f, 0.f};
#pragma unroll
  for (int k = 0; k < 8; k++) v += ((const f32x4*)(part + (size_t)k * BB * CC))[i];
  const f32x4 uo = ((const f32x4*)u)[i];
  f32x4 un;
#pragma unroll
  for (int j = 0; j < 4; j++) {
    const float gu = v[j] + (0.02f * GAMMA) * uo[j];
    const float uu = uo[j] - LR * gu;
    un[j] = fmaxf(uu - (LR * GAMMA), 0.f) + fminf(uu + (LR * GAMMA), 0.f);
  }
  ((f32x4*)u)[i] = un;
  store4bf(ub + (size_t)i * 4, un);
}

// ---- one-time conversion / init kernels ----

__global__ __launch_bounds__(256)
void convtrans_k(const float* __restrict__ src, unsigned short* __restrict__ b,
                 unsigned short* __restrict__ t, int R, int C) {
  __shared__ float tile[64][65];
  const int tid = threadIdx.x;
  const int tr = blockIdx.y * 64;
  const int tc = blockIdx.x * 64;
  const int lr = tid >> 4;
  const int lc = (tid & 15) * 4;
#pragma unroll
  for (int i = 0; i < 4; i++) {
    const float4 v = *(const float4*)(src + (size_t)(tr + lr + 16 * i) * C + tc + lc);
    tile[lr + 16 * i][lc + 0] = v.x;
    tile[lr + 16 * i][lc + 1] = v.y;
    tile[lr + 16 * i][lc + 2] = v.z;
    tile[lr + 16 * i][lc + 3] = v.w;
    store4bf(b + (size_t)(tr + lr + 16 * i) * C + tc + lc, f32x4{v.x, v.y, v.z, v.w});
  }
  __syncthreads();
#pragma unroll
  for (int j = 0; j < 16; j++) {
    const int idx = tid + j * 256;
    const int c = idx >> 6;
    const int r = idx & 63;
    t[(size_t)(tc + c) * R + tr + r] = f2bf(tile[r][c]);
  }
}

__global__ void zero_k(unsigned int* p, int n) {
  const int i = blockIdx.x * blockDim.x + threadIdx.x;
  if (i < n) p[i] = 0u;
}

__global__ void initu_k(const float* __restrict__ u0, float* __restrict__ u,
                        unsigned short* __restrict__ ub, int n) {
  const int i = blockIdx.x * blockDim.x + threadIdx.x;
  if (i < n) {
    const float v = u0[i];
    u[i] = v;
    ub[i] = f2bf(v);
  }
}

__global__ __launch_bounds__(256) void r0_k(const float* __restrict__ inputs,
                                            unsigned short* __restrict__ r) {
  const int i = blockIdx.x * 256 + threadIdx.x;
  const f32x4 v = ((const f32x4*)inputs)[i];
  store4bf(r + (size_t)i * 4, f32x4{0.f, 0.f, 0.f, 0.f} - v);
}

extern "C" void kernel_launch(void* const* d_in, const int* in_sizes, int n_in,
                              void* d_out, int out_size, void* d_ws, size_t ws_size,
                              hipStream_t stream) {
  const float* inputs = (const float*)d_in[0];   // (BB, DD)
  const float* W      = (const float*)d_in[1];   // (KK, DD)
  const float* V      = (const float*)d_in[2];   // (CC, KK)
  const float* u0     = (const float*)d_in[3];   // (BB, CC)
  float* out = (float*)d_out;                    // (BB, DD)

  char* ws = (char*)d_ws;
  size_t off = 0;
  auto alloc = [&](size_t bytes) -> void* {
    void* p = ws + off;
    off += (bytes + 255) & ~(size_t)255;
    return p;
  };
  unsigned short* Wb = (unsigned short*)alloc((size_t)KK * DD * 2);  // W  (KK,DD)
  unsigned short* Wt = (unsigned short*)alloc((size_t)DD * KK * 2);  // W^T (DD,KK)
  unsigned short* Vb = (unsigned short*)alloc((size_t)CC * KK * 2);  // V  (CC,KK)
  unsigned short* Vt = (unsigned short*)alloc((size_t)KK * CC * 2);  // V^T (KK,CC)
  unsigned short* xb = (unsigned short*)alloc((size_t)BB * KK * 2);
  unsigned short* g  = (unsigned short*)alloc((size_t)BB * KK * 2);
  unsigned short* r  = (unsigned short*)alloc((size_t)BB * DD * 2);
  unsigned short* ub = (unsigned short*)alloc((size_t)BB * CC * 2);
  float* x = (float*)alloc((size_t)BB * KK * 4);
  float* u = (float*)alloc((size_t)BB * CC * 4);
  float* part = (float*)alloc((size_t)8 * BB * CC * 4);

  convtrans_k<<<dim3(DD / 64, KK / 64), 256, 0, stream>>>(W, Wb, Wt, KK, DD);
  convtrans_k<<<dim3(KK / 64, CC / 64), 256, 0, stream>>>(V, Vb, Vt, CC, KK);
  zero_k<<<(BB * KK / 2 + 255) / 256, 256, 0, stream>>>((unsigned int*)xb, BB * KK / 2);
  zero_k<<<(BB * KK + 255) / 256, 256, 0, stream>>>((unsigned int*)x, BB * KK);
  initu_k<<<(BB * CC + 255) / 256, 256, 0, stream>>>(u0, u, ub, BB * CC);
  r0_k<<<BB * DD / 4 / 256, 256, 0, stream>>>(inputs, r);

  for (int t = 0; t < 10; t++) {
    if (t > 0) {
      if (t < 9) {
        outr_k<0><<<dim3(DD / 64, BB / 64), 256, 0, stream>>>(xb, Wt, inputs, nullptr, r);
      } else {
        outr_k<1><<<dim3(DD / 64, BB / 64), 256, 0, stream>>>(xb, Wt, nullptr, out, nullptr);
        break;
      }
    }
    zgx_k<<<dim3(KK / 64, BB / 64), 256, 0, stream>>>(ub, Vt, r, Wb, x, xb, g);
    gu_k<<<dim3(CC / 64, BB / 64, 8), 256, 0, stream>>>(g, Vb, part);
    ep_u_k<<<BB * CC / 4 / 256, 256, 0, stream>>>(part, u, ub);
  }
}